// Round 15
// baseline (166.543 us; speedup 1.0000x reference)
//
#include <hip/hip_runtime.h>

#define NTOK 262144   // 64*64*64 tokens per batch
#define NCH  64
#define NB   4

#define TPB   512     // 8 waves
#define TILE  256     // tokens per tile; channel row = 1KB
#define GRIDX 64      // blocks per batch -> 256 total = 1/CU
#define NIT   (NTOK / (GRIDX * TILE))   // 16 tiles per block

// ws layout (floats): S[4][4] @0, m[4][4][64] @16, rc[4][64] @1040
#define WS_S  0
#define WS_M  16
#define WS_RC 1040

typedef float floatx4 __attribute__((ext_vector_type(4)));   // native vec for nontemporal
typedef const __attribute__((address_space(1))) unsigned int* gas1p;
typedef __attribute__((address_space(3))) unsigned int*       las3p;

// Single-x-read fused reduce on async DMA, now TRUE-pipelined:
// per iter: issue stage(t+1) FIRST, then s_waitcnt vmcnt(8) (= stage(t+1)
// outstanding; guarantees stage(t) landed since vmcnt retires in order),
// so the DMA queue never drains at a tile boundary (r14 waited vmcnt(0)
// BEFORE issuing -> bubble every tile). 3 raw barriers/tile:
// B1 tile-visible, B2 es-ready, B3 buffer-release (before next stage).
__global__ __launch_bounds__(TPB)
void ea3d_reduce(const float* __restrict__ x, const float* __restrict__ Wk,
                 float* __restrict__ ws)
{
    __shared__ __align__(16) float buf[2][NCH][TILE];   // 128KB x-tile double buffer
    __shared__ __align__(16) float es[TILE][4];         // 4KB e[t][h]
    __shared__ __align__(16) float wk4[NCH][4];         // Wk transposed
    __shared__ float ssum[8][4];

    const int tid = threadIdx.x;
    const int w   = tid >> 6;
    const int l   = tid & 63;
    const int b   = blockIdx.y;

    if (tid < 256) wk4[tid >> 2][tid & 3] = Wk[(tid & 3) * NCH + (tid >> 2)];
    __syncthreads();

    const float* xb = x + (size_t)b * NCH * NTOK;
    const size_t tokblk = (size_t)blockIdx.x * (TILE * NIT);
    const int    c0 = w << 3;                 // wave stages/m-accumulates ch 8w..8w+8

    float macc[32];                           // macc[i*4+h], channel c0+i
    #pragma unroll
    for (int r = 0; r < 32; ++r) macc[r] = 0.f;
    float sacc[4] = {0.f, 0.f, 0.f, 0.f};

    // DMA one tile's 8 channel rows for this wave: dst uniform row base,
    // src per-lane (16B/lane x 64 lanes = the full 1KB row).
    auto stage = [&](int tt) {
        const size_t t0 = tokblk + (size_t)tt * TILE + (l << 2);
        float* dbase = &buf[tt & 1][c0][0];
        #pragma unroll
        for (int i = 0; i < 8; ++i) {
            const float* src = xb + (size_t)(c0 + i) * NTOK + t0;
            float* dst = dbase + i * TILE;
            __builtin_amdgcn_global_load_lds((gas1p)src, (las3p)dst, 16, 0, 0);
        }
    };

    stage(0);                                 // prologue

    #pragma unroll 1
    for (int t = 0; t < NIT; ++t) {
        // ---- issue next stage BEFORE waiting: DMA queue never drains ----
        if (t + 1 < NIT) {
            stage(t + 1);                     // buf[(t+1)&1] released by B3(t-1)
            asm volatile("s_waitcnt vmcnt(8)" ::: "memory");   // stage(t) landed
        } else {
            asm volatile("s_waitcnt vmcnt(0)" ::: "memory");
        }
        __builtin_amdgcn_s_barrier();                      // B1: tile t visible
        asm volatile("" ::: "memory");

        // ---- keys: lane token tk = w*32+(l&31), channel half (l>>5)*32 ----
        const float* bt = &buf[t & 1][0][0];
        const int tk  = (w << 5) + (l & 31);
        const int ch0 = (l >> 5) << 5;
        float k0 = 0.f, k1 = 0.f, k2 = 0.f, k3 = 0.f;
        #pragma unroll
        for (int j = 0; j < 32; ++j) {
            float  xv = bt[(ch0 + j) * TILE + tk];
            float4 wv = *(const float4*)&wk4[ch0 + j][0];
            k0 += wv.x * xv; k1 += wv.y * xv; k2 += wv.z * xv; k3 += wv.w * xv;
        }
        k0 += __shfl_xor(k0, 32); k1 += __shfl_xor(k1, 32);
        k2 += __shfl_xor(k2, 32); k3 += __shfl_xor(k3, 32);
        float e0 = __expf(k0), e1 = __expf(k1), e2 = __expf(k2), e3 = __expf(k3);
        if (l < 32) {
            *(float4*)&es[tk][0] = make_float4(e0, e1, e2, e3);
            sacc[0] += e0; sacc[1] += e1; sacc[2] += e2; sacc[3] += e3;
        }

        asm volatile("s_waitcnt lgkmcnt(0)" ::: "memory");
        __builtin_amdgcn_s_barrier();                      // B2: es ready
        asm volatile("" ::: "memory");

        // ---- m-phase: lane tokens 4l..4l+3, wave's 8 channels, registers ----
        const int t4 = l << 2;
        float4 ea = *(const float4*)&es[t4 + 0][0];
        float4 eb = *(const float4*)&es[t4 + 1][0];
        float4 ec = *(const float4*)&es[t4 + 2][0];
        float4 ed = *(const float4*)&es[t4 + 3][0];
        #pragma unroll
        for (int i = 0; i < 8; ++i) {
            float4 xv = *(const float4*)&buf[t & 1][c0 + i][t4];
            macc[i*4+0] += ea.x*xv.x + eb.x*xv.y + ec.x*xv.z + ed.x*xv.w;
            macc[i*4+1] += ea.y*xv.x + eb.y*xv.y + ec.y*xv.z + ed.y*xv.w;
            macc[i*4+2] += ea.z*xv.x + eb.z*xv.y + ec.z*xv.z + ed.z*xv.w;
            macc[i*4+3] += ea.w*xv.x + eb.w*xv.y + ec.w*xv.z + ed.w*xv.w;
        }

        asm volatile("s_waitcnt lgkmcnt(0)" ::: "memory");
        __builtin_amdgcn_s_barrier();                      // B3: release buf[t&1]
        asm volatile("" ::: "memory");
    }

    // ---- macc: reduce over 64 lanes (token dim) -> 32 atomics per wave ----
    #pragma unroll
    for (int r = 0; r < 32; ++r) {
        float v = macc[r];
        v += __shfl_xor(v, 1);  v += __shfl_xor(v, 2);
        v += __shfl_xor(v, 4);  v += __shfl_xor(v, 8);
        v += __shfl_xor(v, 16); v += __shfl_xor(v, 32);
        macc[r] = v;
    }
    if (l == 0) {
        float* mb = ws + WS_M + (size_t)(b * 4) * NCH + c0;
        #pragma unroll
        for (int i = 0; i < 8; ++i) {
            #pragma unroll
            for (int h = 0; h < 4; ++h)
                __hip_atomic_fetch_add(mb + h * NCH + i, macc[i*4+h],
                                       __ATOMIC_RELAXED, __HIP_MEMORY_SCOPE_AGENT);
        }
    }

    // ---- S: lanes 0-31 hold per-token sums; reduce within the half-wave ----
    {
        float v0 = sacc[0], v1 = sacc[1], v2 = sacc[2], v3 = sacc[3];
        #pragma unroll
        for (int off = 1; off < 32; off <<= 1) {
            v0 += __shfl_xor(v0, off); v1 += __shfl_xor(v1, off);
            v2 += __shfl_xor(v2, off); v3 += __shfl_xor(v3, off);
        }
        if (l == 0) { ssum[w][0] = v0; ssum[w][1] = v1; ssum[w][2] = v2; ssum[w][3] = v3; }
    }
    __syncthreads();
    if (tid < 4) {
        float s = 0.f;
        #pragma unroll
        for (int w2 = 0; w2 < 8; ++w2) s += ssum[w2][tid];
        __hip_atomic_fetch_add(ws + WS_S + b * 4 + tid, s,
                               __ATOMIC_RELAXED, __HIP_MEMORY_SCOPE_AGENT);
    }
}

// ---------- finalize: context = Wv*(m/S)+bv ; rc = Wr*context + br ----------
__global__ void ea3d_finalize(const float* __restrict__ Wv, const float* __restrict__ bv,
                              const float* __restrict__ Wr, const float* __restrict__ br,
                              float* __restrict__ ws)
{
    __shared__ float ctx[NB * 32];
    const int tid = threadIdx.x;
    if (tid < 128) {
        int b = tid >> 5, hv = tid & 31, h = hv >> 3;
        float inv = 1.0f / ws[WS_S + b * 4 + h];
        const float* m = ws + WS_M + (b * 4 + h) * NCH;
        const float* wvr = Wv + hv * NCH;
        float acc = 0.f;
        #pragma unroll
        for (int c = 0; c < NCH; ++c) acc += wvr[c] * m[c];
        ctx[b * 32 + hv] = acc * inv + bv[hv];
    }
    __syncthreads();
    int b = tid >> 6, c = tid & 63;
    const float* wrr = Wr + c * 32;
    const float* cb  = ctx + b * 32;
    float acc = br[c];
    #pragma unroll
    for (int hv = 0; hv < 32; ++hv) acc += wrr[hv] * cb[hv];
    ws[WS_RC + b * NCH + c] = acc;
}

// ---------- out = x + rc[b][c]  (nontemporal stores: don't evict x) ----------
__global__ __launch_bounds__(256)
void ea3d_add(const float* __restrict__ x, const float* __restrict__ ws,
              float* __restrict__ out)
{
    const int row = blockIdx.y;                 // b*64 + c
    const float rc = ws[WS_RC + row];
    const size_t base = (size_t)row * NTOK;
    const float4*  xp = (const float4*)(x + base);
    floatx4*       op = (floatx4*)(out + base);
    const int nvec = NTOK / 4;
    for (int i = blockIdx.x * blockDim.x + threadIdx.x; i < nvec;
         i += gridDim.x * blockDim.x) {
        float4 v = xp[i];
        floatx4 nv = { v.x + rc, v.y + rc, v.z + rc, v.w + rc };
        __builtin_nontemporal_store(nv, op + i);
    }
}

extern "C" void kernel_launch(void* const* d_in, const int* in_sizes, int n_in,
                              void* d_out, int out_size, void* d_ws, size_t ws_size,
                              hipStream_t stream)
{
    const float* x  = (const float*)d_in[0];
    const float* Wk = (const float*)d_in[1];
    // d_in[2]=bk (cancels in token-softmax); d_in[3]=Wq, d_in[4]=bq (softmax over
    // size-1 head-channel axis -> identically 1.0, so Wq/bq are dead)
    const float* Wv = (const float*)d_in[5];
    const float* bv = (const float*)d_in[6];
    const float* Wr = (const float*)d_in[7];
    const float* br = (const float*)d_in[8];
    float* out = (float*)d_out;
    float* ws  = (float*)d_ws;

    (void)hipMemsetAsync(ws, 0, WS_RC * sizeof(float), stream);  // zero S + m accumulators
    ea3d_reduce<<<dim3(GRIDX, NB), TPB, 0, stream>>>(x, Wk, ws);
    ea3d_finalize<<<1, 256, 0, stream>>>(Wv, bv, Wr, br, ws);
    ea3d_add<<<dim3(32, NB * NCH), 256, 0, stream>>>(x, ws, out);
}

// Round 16
// 164.835 us; speedup vs baseline: 1.0104x; 1.0104x over previous
//
#include <hip/hip_runtime.h>

#define NTOK 262144   // 64*64*64 tokens per batch
#define NCH  64
#define NB   4

#define TPB   512     // 8 waves
#define TILE  512     // tokens per tile; channel row = 2KB (2 consecutive 1KB DMA chunks)
#define GRIDX 64      // blocks per batch -> 256 total = 1/CU
#define NIT   (NTOK / (GRIDX * TILE))   // 8 tiles per block

// ws layout (floats): S[4][4] @0, m[4][4][64] @16, rc[4][64] @1040
#define WS_S  0
#define WS_M  16
#define WS_RC 1040

typedef float floatx4 __attribute__((ext_vector_type(4)));   // native vec for nontemporal
typedef const __attribute__((address_space(1))) unsigned int* gas1p;
typedef __attribute__((address_space(3))) unsigned int*       las3p;

// Single-x-read fused reduce, 2KB DRAM-run staging.
// r14/r15 proved the DMA path (not duty cycle) limits this pattern at ~1KB
// runs (~2.0-2.6 TB/s). Here each channel row is staged as TWO CONSECUTIVE
// 1KB global_load_lds chunks -> DRAM sees 2KB sequential runs per stream.
// Single 128KB buffer (no double buffer fits); drain bubble accepted since
// r15 showed pipelining gains nothing. Keys: 512 threads = 512 tokens, full
// 64-ch dot/thread (no shuffles). m-phase: lane-strided tokens, h-major es
// -> every LDS access conflict-free. VGPR ~70, 1 block/CU.
__global__ __launch_bounds__(TPB)
void ea3d_reduce(const float* __restrict__ x, const float* __restrict__ Wk,
                 float* __restrict__ ws)
{
    __shared__ __align__(16) float buf[NCH][TILE];   // 128KB x-tile (single buffer)
    __shared__ __align__(16) float es2[4][TILE + 8]; // e, h-major (+pad)
    __shared__ __align__(16) float wk4[NCH][4];      // Wk transposed
    __shared__ float ssum[8][4];

    const int tid = threadIdx.x;
    const int w   = tid >> 6;
    const int l   = tid & 63;
    const int b   = blockIdx.y;

    if (tid < 256) wk4[tid >> 2][tid & 3] = Wk[(tid & 3) * NCH + (tid >> 2)];
    __syncthreads();

    const float* xb = x + (size_t)b * NCH * NTOK;
    const size_t tokblk = (size_t)blockIdx.x * (TILE * NIT);
    const int    c0 = w << 3;                 // wave stages / m-accumulates ch 8w..8w+8

    float macc[32];                           // macc[i*4+h], channel c0+i
    #pragma unroll
    for (int r = 0; r < 32; ++r) macc[r] = 0.f;
    float sacc[4] = {0.f, 0.f, 0.f, 0.f};

    // Stage one tile: per wave 8 channel rows, each as 2 consecutive 1KB DMA
    // chunks (lane-swept src; WAVE-UNIFORM LDS dst base, HW adds lane*16).
    auto stage = [&](int tt) {
        const size_t t0 = tokblk + (size_t)tt * TILE + (l << 2);
        #pragma unroll
        for (int i = 0; i < 8; ++i) {
            const float* src = xb + (size_t)(c0 + i) * NTOK + t0;
            __builtin_amdgcn_global_load_lds((gas1p)src,         (las3p)&buf[c0 + i][0],   16, 0, 0);
            __builtin_amdgcn_global_load_lds((gas1p)(src + 256), (las3p)&buf[c0 + i][256], 16, 0, 0);
        }
    };

    stage(0);                                 // prologue

    #pragma unroll 1
    for (int t = 0; t < NIT; ++t) {
        asm volatile("s_waitcnt vmcnt(0)" ::: "memory");   // this wave's DMAs landed
        __builtin_amdgcn_s_barrier();                      // B1: whole tile visible
        asm volatile("" ::: "memory");

        // ---- keys: thread tid -> token tk = tid, full 64-channel dot ----
        {
            const int tk = tid;
            float k0 = 0.f, k1 = 0.f, k2 = 0.f, k3 = 0.f;
            #pragma unroll 16
            for (int c = 0; c < NCH; ++c) {
                float  xv = buf[c][tk];
                float4 wv = *(const float4*)&wk4[c][0];   // uniform addr -> broadcast
                k0 += wv.x * xv; k1 += wv.y * xv; k2 += wv.z * xv; k3 += wv.w * xv;
            }
            float e0 = __expf(k0), e1 = __expf(k1), e2 = __expf(k2), e3 = __expf(k3);
            es2[0][tk] = e0; es2[1][tk] = e1; es2[2][tk] = e2; es2[3][tk] = e3;
            sacc[0] += e0; sacc[1] += e1; sacc[2] += e2; sacc[3] += e3;
        }

        asm volatile("s_waitcnt lgkmcnt(0)" ::: "memory");
        __builtin_amdgcn_s_barrier();                      // B2: es ready
        asm volatile("" ::: "memory");

        // ---- m-phase: wave's 8 channels, lane tokens {l+64s} (conflict-free) ----
        #pragma unroll
        for (int s = 0; s < 8; ++s) {
            const int tk = l + (s << 6);
            float e0 = es2[0][tk], e1 = es2[1][tk], e2 = es2[2][tk], e3 = es2[3][tk];
            #pragma unroll
            for (int i = 0; i < 8; ++i) {
                float xv = buf[c0 + i][tk];
                macc[i*4+0] += e0 * xv;
                macc[i*4+1] += e1 * xv;
                macc[i*4+2] += e2 * xv;
                macc[i*4+3] += e3 * xv;
            }
        }

        asm volatile("s_waitcnt lgkmcnt(0)" ::: "memory");
        __builtin_amdgcn_s_barrier();                      // B3: buf free for overwrite
        asm volatile("" ::: "memory");

        if (t + 1 < NIT) stage(t + 1);
    }

    // ---- macc: reduce over 64 lanes (token dim) -> 32 atomics per wave ----
    #pragma unroll
    for (int r = 0; r < 32; ++r) {
        float v = macc[r];
        v += __shfl_xor(v, 1);  v += __shfl_xor(v, 2);
        v += __shfl_xor(v, 4);  v += __shfl_xor(v, 8);
        v += __shfl_xor(v, 16); v += __shfl_xor(v, 32);
        macc[r] = v;
    }
    if (l == 0) {
        float* mb = ws + WS_M + (size_t)(b * 4) * NCH + c0;
        #pragma unroll
        for (int i = 0; i < 8; ++i) {
            #pragma unroll
            for (int h = 0; h < 4; ++h)
                __hip_atomic_fetch_add(mb + h * NCH + i, macc[i*4+h],
                                       __ATOMIC_RELAXED, __HIP_MEMORY_SCOPE_AGENT);
        }
    }

    // ---- S: every thread summed its own tokens; reduce wave -> block -> global ----
    {
        float v0 = sacc[0], v1 = sacc[1], v2 = sacc[2], v3 = sacc[3];
        #pragma unroll
        for (int off = 1; off < 64; off <<= 1) {
            v0 += __shfl_xor(v0, off); v1 += __shfl_xor(v1, off);
            v2 += __shfl_xor(v2, off); v3 += __shfl_xor(v3, off);
        }
        if (l == 0) { ssum[w][0] = v0; ssum[w][1] = v1; ssum[w][2] = v2; ssum[w][3] = v3; }
    }
    __syncthreads();
    if (tid < 4) {
        float s = 0.f;
        #pragma unroll
        for (int w2 = 0; w2 < 8; ++w2) s += ssum[w2][tid];
        __hip_atomic_fetch_add(ws + WS_S + b * 4 + tid, s,
                               __ATOMIC_RELAXED, __HIP_MEMORY_SCOPE_AGENT);
    }
}

// ---------- finalize: context = Wv*(m/S)+bv ; rc = Wr*context + br ----------
__global__ void ea3d_finalize(const float* __restrict__ Wv, const float* __restrict__ bv,
                              const float* __restrict__ Wr, const float* __restrict__ br,
                              float* __restrict__ ws)
{
    __shared__ float ctx[NB * 32];
    const int tid = threadIdx.x;
    if (tid < 128) {
        int b = tid >> 5, hv = tid & 31, h = hv >> 3;
        float inv = 1.0f / ws[WS_S + b * 4 + h];
        const float* m = ws + WS_M + (b * 4 + h) * NCH;
        const float* wvr = Wv + hv * NCH;
        float acc = 0.f;
        #pragma unroll
        for (int c = 0; c < NCH; ++c) acc += wvr[c] * m[c];
        ctx[b * 32 + hv] = acc * inv + bv[hv];
    }
    __syncthreads();
    int b = tid >> 6, c = tid & 63;
    const float* wrr = Wr + c * 32;
    const float* cb  = ctx + b * 32;
    float acc = br[c];
    #pragma unroll
    for (int hv = 0; hv < 32; ++hv) acc += wrr[hv] * cb[hv];
    ws[WS_RC + b * NCH + c] = acc;
}

// ---------- out = x + rc[b][c]  (nontemporal stores: don't evict x) ----------
__global__ __launch_bounds__(256)
void ea3d_add(const float* __restrict__ x, const float* __restrict__ ws,
              float* __restrict__ out)
{
    const int row = blockIdx.y;                 // b*64 + c
    const float rc = ws[WS_RC + row];
    const size_t base = (size_t)row * NTOK;
    const float4*  xp = (const float4*)(x + base);
    floatx4*       op = (floatx4*)(out + base);
    const int nvec = NTOK / 4;
    for (int i = blockIdx.x * blockDim.x + threadIdx.x; i < nvec;
         i += gridDim.x * blockDim.x) {
        float4 v = xp[i];
        floatx4 nv = { v.x + rc, v.y + rc, v.z + rc, v.w + rc };
        __builtin_nontemporal_store(nv, op + i);
    }
}

extern "C" void kernel_launch(void* const* d_in, const int* in_sizes, int n_in,
                              void* d_out, int out_size, void* d_ws, size_t ws_size,
                              hipStream_t stream)
{
    const float* x  = (const float*)d_in[0];
    const float* Wk = (const float*)d_in[1];
    // d_in[2]=bk (cancels in token-softmax); d_in[3]=Wq, d_in[4]=bq (softmax over
    // size-1 head-channel axis -> identically 1.0, so Wq/bq are dead)
    const float* Wv = (const float*)d_in[5];
    const float* bv = (const float*)d_in[6];
    const float* Wr = (const float*)d_in[7];
    const float* br = (const float*)d_in[8];
    float* out = (float*)d_out;
    float* ws  = (float*)d_ws;

    (void)hipMemsetAsync(ws, 0, WS_RC * sizeof(float), stream);  // zero S + m accumulators
    ea3d_reduce<<<dim3(GRIDX, NB), TPB, 0, stream>>>(x, Wk, ws);
    ea3d_finalize<<<1, 256, 0, stream>>>(Wv, bv, Wr, br, ws);
    ea3d_add<<<dim3(32, NB * NCH), 256, 0, stream>>>(x, ws, out);
}